// Round 4
// baseline (229.627 us; speedup 1.0000x reference)
//
#include <hip/hip_runtime.h>
#include <math.h>

#define DIM   128
#define SLICE (DIM*DIM)       // 16384
#define VOL   (DIM*DIM*DIM)   // 2097152
#define NK    4
#define SSTR  33              // staging row stride in float4
#define WSS   32              // ws accumulator stride in floats (128 B = own cache line)
#define DONE  24              // completion ticket slot (x WSS)
#define TICK  26              // per-volume phase-A ticket slots 26..33 (x WSS)

// Gaussian taps exp(-x^2/(2*5^2)), x=-4..4 (unnormalized, matches reference)
__constant__ float c_g[9] = {
    0.72614904f, 0.83527021f, 0.92311635f, 0.98019867f, 1.0f,
    0.98019867f, 0.92311635f, 0.83527021f, 0.72614904f
};

// ws layout (floats, stride WSS => one 128-B line per slot):
//   slot 0..7   : sumP  per vol
//   slot 8..15  : sumIP per vol
//   slot 16..19 : num per class
//   slot 20..23 : den per class
//   slot 24     : final ticket (uint)
//   slot 26..33 : per-volume phase-A tickets (uint)

// ONE kernel, 512 blocks = (vol 8) x (h-strip 16) x (d-quarter 4).
// Phase A: each block sums P, I*P over its OWN output region (8 rows x 32
// slices x 128 cols); the 64 blocks of a volume tile it exactly. Per-volume
// ticket rendezvous (all 512 blocks co-resident: launch_bounds(256,2) => >=2
// blocks/CU, grid = 2x256). Phase B: round-0 fused blur body (82 us verified).
// Final: last block through the DONE ticket computes the loss.
__global__ __launch_bounds__(256, 2) void k_all(
    const float* __restrict__ labels, const float* __restrict__ inputs,
    float* __restrict__ red, float* __restrict__ out)
{
    __shared__ float4 sW[2][16*SSTR + 8];
    __shared__ float sN[4], sD[4];
    __shared__ float sMean;

    const int dq    = blockIdx.x & 3;
    const int strip = (blockIdx.x >> 2) & 15;
    const int vol   = blockIdx.x >> 6;
    const int b = vol >> 2, kcls = vol & 3;
    const int d0 = dq * 32;
    const int t  = threadIdx.x;
    const float g1 = c_g[5], g2 = c_g[6], g3 = c_g[7], g4 = c_g[8];
    const float4 z4 = make_float4(0.f, 0.f, 0.f, 0.f);

    // ---------------- Phase A: per-volume sums via per-block partials ----------------
    {
        const int rr = t >> 5, cc = t & 31;                 // row 0..7, quad 0..31
        const size_t roff = (size_t)d0*(SLICE/4) + (size_t)(strip*8)*(DIM/4)
                          + (size_t)rr*(DIM/4) + cc;
        const float4* __restrict__ Pa = (const float4*)labels + (size_t)vol*(VOL/4) + roff;
        const float4* __restrict__ Ia = (const float4*)inputs + (size_t)b  *(VOL/4) + roff;
        float sp = 0.f, sip = 0.f;
        #pragma unroll 4
        for (int s = 0; s < 32; ++s) {
            const float4 p  = Pa[(size_t)s*(SLICE/4)];
            const float4 iv = Ia[(size_t)s*(SLICE/4)];
            sp  += p.x + p.y + p.z + p.w;
            sip += p.x*iv.x + p.y*iv.y + p.z*iv.z + p.w*iv.w;
        }
        #pragma unroll
        for (int o = 32; o; o >>= 1) { sp += __shfl_down(sp, o); sip += __shfl_down(sip, o); }
        if ((t & 63) == 0) { sN[t >> 6] = sp; sD[t >> 6] = sip; }
        __syncthreads();
        if (t == 0) {
            atomicAdd(&red[vol*WSS],     sN[0]+sN[1]+sN[2]+sN[3]);
            atomicAdd(&red[(8+vol)*WSS], sD[0]+sD[1]+sD[2]+sD[3]);
            __threadfence();
            atomicAdd((unsigned int*)&red[(TICK+vol)*WSS], 1u);
            // rendezvous: wait for all 64 blocks of this volume
            while (__hip_atomic_load((unsigned int*)&red[(TICK+vol)*WSS],
                                     __ATOMIC_ACQUIRE, __HIP_MEMORY_SCOPE_AGENT) < 64u)
                __builtin_amdgcn_s_sleep(2);
            const float sumP  = atomicAdd(&red[vol*WSS],     0.0f);  // coherent RMW read
            const float sumIP = atomicAdd(&red[(8+vol)*WSS], 0.0f);
            sMean = sumIP / (sumP + 20.97152f);
        }
        __syncthreads();
    }
    const float mean = sMean;

    // ---------------- Phase B: fused wh-blur + d-blur + weights + reduction ----------------
    const float* __restrict__ src = labels + (size_t)vol*VOL;

    // two w-blur sites per thread: (r0,c0) and (r0+8,c0), staged rows 0..15
    const int r0 = t >> 5, c0 = t & 31;
    const int r1 = r0 + 8;
    // h-blur / output site: global row strip*8+ho, float4 col wq
    const int ho = t >> 5, wq = t & 31;

    const int hA = strip*8 - 4 + r0;
    const int hB = strip*8 - 4 + r1;
    const bool vA = (unsigned)hA < 128u;
    const bool vB = (unsigned)hB < 128u;
    const float4* __restrict__ rowA = (const float4*)(src + (size_t)(vA ? hA : 0)*DIM);
    const float4* __restrict__ rowB = (const float4*)(src + (size_t)(vB ? hB : 0)*DIM);

    const size_t ob4 = (size_t)(strip*8 + ho)*(DIM/4) + wq;
    const float4* __restrict__ P4 = (const float4*)src + ob4;
    const float4* __restrict__ I4 = (const float4*)(inputs + (size_t)b*VOL) + ob4;

    float4 ring[9];
    #pragma unroll
    for (int i = 0; i < 9; ++i) ring[i] = z4;
    float numAcc = 0.f, denAcc = 0.f;

    auto ldA = [&](int s, float4& pv, float4& cv, float4& nx) {
        pv = cv = nx = z4;
        if (vA && (unsigned)s < 128u) {
            const float4* rp = rowA + (size_t)s*(SLICE/4);
            cv = rp[c0];
            if (c0 > 0)  pv = rp[c0-1];
            if (c0 < 31) nx = rp[c0+1];
        }
    };
    auto ldB = [&](int s, float4& pv, float4& cv, float4& nx) {
        pv = cv = nx = z4;
        if (vB && (unsigned)s < 128u) {
            const float4* rp = rowB + (size_t)s*(SLICE/4);
            cv = rp[c0];
            if (c0 > 0)  pv = rp[c0-1];
            if (c0 < 31) nx = rp[c0+1];
        }
    };

    float4 Apv, Acv, Anx, Bpv, Bcv, Bnx;
    ldA(d0-4, Apv, Acv, Anx);
    ldB(d0-4, Bpv, Bcv, Bnx);

    #pragma unroll 2
    for (int s = d0-4; s < d0+36; ++s) {
        const float4 apv=Apv, acv=Acv, anx=Anx, bpv=Bpv, bcv=Bcv, bnx=Bnx;
        ldA(s+1, Apv, Acv, Anx);                 // prefetch next slice windows
        ldB(s+1, Bpv, Bcv, Bnx);
        float4 pc = z4, ic = z4;
        const bool outStep = (s >= d0+4);
        if (outStep) {                           // prefetch output-voxel P, I
            pc = P4[(size_t)(s-4)*(SLICE/4)];
            ic = I4[(size_t)(s-4)*(SLICE/4)];
        }
        const int buf = s & 1;
        {   // w-blur site A
            float4 o;
            o.x = acv.x + g1*(apv.w+acv.y) + g2*(apv.z+acv.z) + g3*(apv.y+acv.w) + g4*(apv.x+anx.x);
            o.y = acv.y + g1*(acv.x+acv.z) + g2*(apv.w+acv.w) + g3*(apv.z+anx.x) + g4*(apv.y+anx.y);
            o.z = acv.z + g1*(acv.y+acv.w) + g2*(acv.x+anx.x) + g3*(apv.w+anx.y) + g4*(apv.z+anx.z);
            o.w = acv.w + g1*(acv.z+anx.x) + g2*(acv.y+anx.y) + g3*(acv.x+anx.z) + g4*(apv.w+anx.w);
            sW[buf][r0*SSTR + c0] = o;
        }
        {   // w-blur site B
            float4 o;
            o.x = bcv.x + g1*(bpv.w+bcv.y) + g2*(bpv.z+bcv.z) + g3*(bpv.y+bcv.w) + g4*(bpv.x+bnx.x);
            o.y = bcv.y + g1*(bcv.x+bcv.z) + g2*(bpv.w+bcv.w) + g3*(bpv.z+bnx.x) + g4*(bpv.y+bnx.y);
            o.z = bcv.z + g1*(bcv.y+bcv.w) + g2*(bcv.x+bnx.x) + g3*(bpv.w+bnx.y) + g4*(bpv.z+bnx.z);
            o.w = bcv.w + g1*(bcv.z+bnx.x) + g2*(bcv.y+bnx.y) + g3*(bcv.x+bnx.z) + g4*(bpv.w+bnx.w);
            sW[buf][r1*SSTR + c0] = o;
        }
        __syncthreads();                         // one barrier per step
        // h-blur at (ho,wq): staged rows (ho+4) +/- dt
        float4 acc = sW[buf][(ho+4)*SSTR + wq];
        #pragma unroll
        for (int dt = 1; dt <= 4; ++dt) {
            const float g = c_g[4+dt];
            const float4 u = sW[buf][(ho+4-dt)*SSTR + wq];
            const float4 v = sW[buf][(ho+4+dt)*SSTR + wq];
            acc.x += g*(u.x+v.x); acc.y += g*(u.y+v.y);
            acc.z += g*(u.z+v.z); acc.w += g*(u.w+v.w);
        }
        #pragma unroll
        for (int i = 0; i < 8; ++i) ring[i] = ring[i+1];
        ring[8] = acc;
        if (outStep) {
            float4 B = ring[4];
            #pragma unroll
            for (int dt = 1; dt <= 4; ++dt) {
                const float g = c_g[4+dt];
                B.x += g*(ring[4+dt].x + ring[4-dt].x);
                B.y += g*(ring[4+dt].y + ring[4-dt].y);
                B.z += g*(ring[4+dt].z + ring[4-dt].z);
                B.w += g*(ring[4+dt].w + ring[4-dt].w);
            }
            { float df = ic.x - mean; df *= df; const float bw = B.x * __expf(-df*df); numAcc += bw*pc.x; denAcc += bw; }
            { float df = ic.y - mean; df *= df; const float bw = B.y * __expf(-df*df); numAcc += bw*pc.y; denAcc += bw; }
            { float df = ic.z - mean; df *= df; const float bw = B.z * __expf(-df*df); numAcc += bw*pc.z; denAcc += bw; }
            { float df = ic.w - mean; df *= df; const float bw = B.w * __expf(-df*df); numAcc += bw*pc.w; denAcc += bw; }
        }
    }

    #pragma unroll
    for (int o = 32; o; o >>= 1) { numAcc += __shfl_down(numAcc, o); denAcc += __shfl_down(denAcc, o); }
    if ((t & 63) == 0) { sN[t >> 6] = numAcc; sD[t >> 6] = denAcc; }
    __syncthreads();
    if (t == 0) {
        atomicAdd(&red[(16+kcls)*WSS], sN[0]+sN[1]+sN[2]+sN[3]);
        atomicAdd(&red[(20+kcls)*WSS], sD[0]+sD[1]+sD[2]+sD[3]);
        __threadfence();
        const unsigned old = atomicAdd((unsigned int*)&red[DONE*WSS], 1u);
        if (old == 511u) {
            float loss = 0.f;
            #pragma unroll
            for (int k = 0; k < 4; ++k) {
                const float nu = atomicAdd(&red[(16+k)*WSS], 0.0f);
                const float de = atomicAdd(&red[(20+k)*WSS], 0.0f);
                loss += fabsf(nu / (de + 1e-6f));
            }
            out[0] = (float)NK - loss;
        }
    }
}

extern "C" void kernel_launch(void* const* d_in, const int* in_sizes, int n_in,
                              void* d_out, int out_size, void* d_ws, size_t ws_size,
                              hipStream_t stream)
{
    const float* labels = (const float*)d_in[0];   // (2,4,128,128,128)
    const float* inputs = (const float*)d_in[1];   // (2,1,128,128,128)
    float* out = (float*)d_out;
    float* red = (float*)d_ws;                     // 34 slots x 32-float stride

    hipMemsetAsync(red, 0, 34*WSS*sizeof(float), stream);
    k_all<<<8*16*4, 256, 0, stream>>>(labels, inputs, red, out);
}

// Round 6
// 192.280 us; speedup vs baseline: 1.1942x; 1.1942x over previous
//
#include <hip/hip_runtime.h>
#include <math.h>

#define DIM   128
#define SLICE (DIM*DIM)       // 16384
#define VOL   (DIM*DIM*DIM)   // 2097152
#define NK    4
#define SW9   9               // per-wave staging row stride in float4 (8 + 1 pad)
#define WSS   32              // ws accumulator stride in floats (128 B = own line)
#define DONE  24              // completion ticket slot (x WSS)

// Gaussian taps exp(-x^2/(2*5^2)), x=-4..4 (unnormalized, matches reference)
__constant__ float c_g[9] = {
    0.72614904f, 0.83527021f, 0.92311635f, 0.98019867f, 1.0f,
    0.98019867f, 0.92311635f, 0.83527021f, 0.72614904f
};

// ws layout (floats, stride WSS => one 128-B line per slot):
//   slot 0..7   : sumP  per vol
//   slot 8..15  : sumIP per vol
//   slot 16..19 : num per class
//   slot 20..23 : den per class
//   slot 24     : final ticket (uint)

// K1: pure-stream sums (round-0 verified). 1024 blocks.
__global__ __launch_bounds__(256) void k_sums(
    const float* __restrict__ labels, const float* __restrict__ inputs,
    float* __restrict__ red)
{
    const int b     = blockIdx.x >> 9;
    const int chunk = blockIdx.x & 511;
    const int t     = threadIdx.x;
    const size_t off4 = (size_t)chunk*1024 + t;
    const float4* __restrict__ I4 = (const float4*)inputs + (size_t)b*(VOL/4) + off4;
    const float4* __restrict__ L4 = (const float4*)labels;
    float sp[4] = {0,0,0,0}, sip[4] = {0,0,0,0};
    #pragma unroll
    for (int j = 0; j < 4; ++j) {
        const float4 iv = I4[j*256];
        #pragma unroll
        for (int k = 0; k < 4; ++k) {
            const float4 p = L4[(size_t)(b*NK + k)*(VOL/4) + off4 + j*256];
            sp[k]  += p.x + p.y + p.z + p.w;
            sip[k] += p.x*iv.x + p.y*iv.y + p.z*iv.z + p.w*iv.w;
        }
    }
    #pragma unroll
    for (int k = 0; k < 4; ++k) {
        #pragma unroll
        for (int o = 32; o; o >>= 1) {
            sp[k]  += __shfl_down(sp[k],  o);
            sip[k] += __shfl_down(sip[k], o);
        }
    }
    __shared__ float sB[8][4];
    const int wid = t >> 6;
    if ((t & 63) == 0) {
        #pragma unroll
        for (int k = 0; k < 4; ++k) { sB[k][wid] = sp[k]; sB[4+k][wid] = sip[k]; }
    }
    __syncthreads();
    if (t < 8) {
        const float v = sB[t][0] + sB[t][1] + sB[t][2] + sB[t][3];
        atomicAdd(&red[((t < 4 ? 0 : 8) + b*NK + (t & 3))*WSS], v);
    }
}

// K2: fused wh-blur + d-blur + weights + reduction + final (ticket).
// Grid 512 = (vol 8) x (strip 16) x (d-quarter 4), 256 threads = 4 waves.
// WAVE-PRIVATE staging: wave w owns w-quarter w (8 f4 cols) of the strip's
// 8 output rows; stages 16 rows x 8 f4 in its own LDS region. All LDS
// dependencies are intra-wave (DS pipe is in-order per wave) => NO
// __syncthreads in the 40-step loop. wave_barrier() = compile-time fence
// only, 0 cycles. Per-lane work identical to the verified round-0 body.
__global__ __launch_bounds__(256, 2) void k_fused(
    const float* __restrict__ labels, const float* __restrict__ inputs,
    float* __restrict__ red, float* __restrict__ out)
{
    __shared__ float4 sWall[4][16*SW9];
    __shared__ float sN[4], sD[4];

    const int dq    = blockIdx.x & 3;
    const int strip = (blockIdx.x >> 2) & 15;
    const int vol   = blockIdx.x >> 6;
    const int b = vol >> 2, kcls = vol & 3;
    const int d0 = dq * 32;
    const int t    = threadIdx.x;
    const int wave = t >> 6, lane = t & 63;
    const float g1 = c_g[5], g2 = c_g[6], g3 = c_g[7], g4 = c_g[8];
    const float4 z4 = make_float4(0.f, 0.f, 0.f, 0.f);

    float4* __restrict__ sWv = sWall[wave];

    const float* __restrict__ src = labels + (size_t)vol*VOL;
    const float mean = red[(8+vol)*WSS] / (red[vol*WSS] + 20.97152f);

    // staging sites: rows r0, r0+8 at local f4-col c0 (global col gc)
    const int c0 = lane & 7, r0 = lane >> 3;
    const int r1 = r0 + 8;
    const int gc = wave*8 + c0;                // global f4 col 0..31
    // output site: global row strip*8+ho, local col wqc (global gco)
    const int ho = lane >> 3, wqc = lane & 7;
    const int gco = wave*8 + wqc;

    const int hA = strip*8 - 4 + r0;
    const int hB = strip*8 - 4 + r1;
    const bool vA = (unsigned)hA < 128u;
    const bool vB = (unsigned)hB < 128u;
    const float4* __restrict__ rowA = (const float4*)(src + (size_t)(vA ? hA : 0)*DIM);
    const float4* __restrict__ rowB = (const float4*)(src + (size_t)(vB ? hB : 0)*DIM);

    const size_t ob4 = (size_t)(strip*8 + ho)*(DIM/4) + gco;
    const float4* __restrict__ P4 = (const float4*)src + ob4;
    const float4* __restrict__ I4 = (const float4*)(inputs + (size_t)b*VOL) + ob4;

    float4 ring[9];
    #pragma unroll
    for (int i = 0; i < 9; ++i) ring[i] = z4;
    float numAcc = 0.f, denAcc = 0.f;

    auto ldA = [&](int s, float4& pv, float4& cv, float4& nx) {
        pv = cv = nx = z4;
        if (vA && (unsigned)s < 128u) {
            const float4* rp = rowA + (size_t)s*(SLICE/4);
            cv = rp[gc];
            if (gc > 0)  pv = rp[gc-1];
            if (gc < 31) nx = rp[gc+1];
        }
    };
    auto ldB = [&](int s, float4& pv, float4& cv, float4& nx) {
        pv = cv = nx = z4;
        if (vB && (unsigned)s < 128u) {
            const float4* rp = rowB + (size_t)s*(SLICE/4);
            cv = rp[gc];
            if (gc > 0)  pv = rp[gc-1];
            if (gc < 31) nx = rp[gc+1];
        }
    };

    float4 Apv, Acv, Anx, Bpv, Bcv, Bnx;
    ldA(d0-4, Apv, Acv, Anx);
    ldB(d0-4, Bpv, Bcv, Bnx);

    #pragma unroll 2
    for (int s = d0-4; s < d0+36; ++s) {
        const float4 apv=Apv, acv=Acv, anx=Anx, bpv=Bpv, bcv=Bcv, bnx=Bnx;
        ldA(s+1, Apv, Acv, Anx);                 // prefetch next slice windows
        ldB(s+1, Bpv, Bcv, Bnx);
        float4 pc = z4, ic = z4;
        const bool outStep = (s >= d0+4);
        if (outStep) {                           // prefetch output-voxel P, I
            pc = P4[(size_t)(s-4)*(SLICE/4)];
            ic = I4[(size_t)(s-4)*(SLICE/4)];
        }
        {   // w-blur site A -> wave-private staging
            float4 o;
            o.x = acv.x + g1*(apv.w+acv.y) + g2*(apv.z+acv.z) + g3*(apv.y+acv.w) + g4*(apv.x+anx.x);
            o.y = acv.y + g1*(acv.x+acv.z) + g2*(apv.w+acv.w) + g3*(apv.z+anx.x) + g4*(apv.y+anx.y);
            o.z = acv.z + g1*(acv.y+acv.w) + g2*(acv.x+anx.x) + g3*(apv.w+anx.y) + g4*(apv.z+anx.z);
            o.w = acv.w + g1*(acv.z+anx.x) + g2*(acv.y+anx.y) + g3*(acv.x+anx.z) + g4*(apv.w+anx.w);
            sWv[r0*SW9 + c0] = o;
        }
        {   // w-blur site B
            float4 o;
            o.x = bcv.x + g1*(bpv.w+bcv.y) + g2*(bpv.z+bcv.z) + g3*(bpv.y+bcv.w) + g4*(bpv.x+bnx.x);
            o.y = bcv.y + g1*(bcv.x+bcv.z) + g2*(bpv.w+bcv.w) + g3*(bpv.z+bnx.x) + g4*(bpv.y+bnx.y);
            o.z = bcv.z + g1*(bcv.y+bcv.w) + g2*(bcv.x+bnx.x) + g3*(bpv.w+bnx.y) + g4*(bpv.z+bnx.z);
            o.w = bcv.w + g1*(bcv.z+bnx.x) + g2*(bcv.y+bnx.y) + g3*(bcv.x+bnx.z) + g4*(bpv.w+bnx.w);
            sWv[r1*SW9 + c0] = o;
        }
        __builtin_amdgcn_wave_barrier();         // compiler fence: writes before reads
        // h-blur at (ho,wqc): staged rows (ho+4) +/- dt (all intra-wave data)
        float4 acc = sWv[(ho+4)*SW9 + wqc];
        #pragma unroll
        for (int dt = 1; dt <= 4; ++dt) {
            const float g = c_g[4+dt];
            const float4 u = sWv[(ho+4-dt)*SW9 + wqc];
            const float4 v = sWv[(ho+4+dt)*SW9 + wqc];
            acc.x += g*(u.x+v.x); acc.y += g*(u.y+v.y);
            acc.z += g*(u.z+v.z); acc.w += g*(u.w+v.w);
        }
        __builtin_amdgcn_wave_barrier();         // reads before next step's writes
        #pragma unroll
        for (int i = 0; i < 8; ++i) ring[i] = ring[i+1];
        ring[8] = acc;
        if (outStep) {
            float4 B = ring[4];
            #pragma unroll
            for (int dt = 1; dt <= 4; ++dt) {
                const float g = c_g[4+dt];
                B.x += g*(ring[4+dt].x + ring[4-dt].x);
                B.y += g*(ring[4+dt].y + ring[4-dt].y);
                B.z += g*(ring[4+dt].z + ring[4-dt].z);
                B.w += g*(ring[4+dt].w + ring[4-dt].w);
            }
            { float df = ic.x - mean; df *= df; const float bw = B.x * __expf(-df*df); numAcc += bw*pc.x; denAcc += bw; }
            { float df = ic.y - mean; df *= df; const float bw = B.y * __expf(-df*df); numAcc += bw*pc.y; denAcc += bw; }
            { float df = ic.z - mean; df *= df; const float bw = B.z * __expf(-df*df); numAcc += bw*pc.z; denAcc += bw; }
            { float df = ic.w - mean; df *= df; const float bw = B.w * __expf(-df*df); numAcc += bw*pc.w; denAcc += bw; }
        }
    }

    #pragma unroll
    for (int o = 32; o; o >>= 1) { numAcc += __shfl_down(numAcc, o); denAcc += __shfl_down(denAcc, o); }
    if (lane == 0) { sN[wave] = numAcc; sD[wave] = denAcc; }
    __syncthreads();
    if (t == 0) {
        atomicAdd(&red[(16+kcls)*WSS], sN[0]+sN[1]+sN[2]+sN[3]);
        atomicAdd(&red[(20+kcls)*WSS], sD[0]+sD[1]+sD[2]+sD[3]);
        __threadfence();
        const unsigned old = atomicAdd((unsigned int*)&red[DONE*WSS], 1u);
        if (old == 511u) {                       // grid = 512 blocks
            float loss = 0.f;
            #pragma unroll
            for (int k = 0; k < 4; ++k) {
                const float nu = atomicAdd(&red[(16+k)*WSS], 0.0f);
                const float de = atomicAdd(&red[(20+k)*WSS], 0.0f);
                loss += fabsf(nu / (de + 1e-6f));
            }
            out[0] = (float)NK - loss;
        }
    }
}

extern "C" void kernel_launch(void* const* d_in, const int* in_sizes, int n_in,
                              void* d_out, int out_size, void* d_ws, size_t ws_size,
                              hipStream_t stream)
{
    const float* labels = (const float*)d_in[0];   // (2,4,128,128,128)
    const float* inputs = (const float*)d_in[1];   // (2,1,128,128,128)
    float* out = (float*)d_out;
    float* red = (float*)d_ws;                     // 25 slots x 32-float stride

    hipMemsetAsync(red, 0, 25*WSS*sizeof(float), stream);
    k_sums<<<2*512, 256, 0, stream>>>(labels, inputs, red);
    k_fused<<<8*16*4, 256, 0, stream>>>(labels, inputs, red, out);
}

// Round 7
// 185.397 us; speedup vs baseline: 1.2386x; 1.0371x over previous
//
#include <hip/hip_runtime.h>
#include <math.h>

#define DIM   128
#define SLICE (DIM*DIM)       // 16384
#define VOL   (DIM*DIM*DIM)   // 2097152
#define NK    4
#define SSTR  33              // staging row stride in float4
#define WSS   32              // ws accumulator stride in floats (128 B = own line)
#define DONE  24              // completion ticket slot (x WSS)

// Gaussian taps exp(-x^2/(2*5^2)), x=-4..4 (unnormalized, matches reference)
__constant__ float c_g[9] = {
    0.72614904f, 0.83527021f, 0.92311635f, 0.98019867f, 1.0f,
    0.98019867f, 0.92311635f, 0.83527021f, 0.72614904f
};

// ws layout (floats, stride WSS => one 128-B line per slot):
//   slot 0..7   : sumP  per vol
//   slot 8..15  : sumIP per vol
//   slot 16..19 : num per class
//   slot 20..23 : den per class
//   slot 24     : final ticket (uint)

// K1: pure-stream sums (round-0 verified). 1024 blocks.
__global__ __launch_bounds__(256) void k_sums(
    const float* __restrict__ labels, const float* __restrict__ inputs,
    float* __restrict__ red)
{
    const int b     = blockIdx.x >> 9;
    const int chunk = blockIdx.x & 511;
    const int t     = threadIdx.x;
    const size_t off4 = (size_t)chunk*1024 + t;
    const float4* __restrict__ I4 = (const float4*)inputs + (size_t)b*(VOL/4) + off4;
    const float4* __restrict__ L4 = (const float4*)labels;
    float sp[4] = {0,0,0,0}, sip[4] = {0,0,0,0};
    #pragma unroll
    for (int j = 0; j < 4; ++j) {
        const float4 iv = I4[j*256];
        #pragma unroll
        for (int k = 0; k < 4; ++k) {
            const float4 p = L4[(size_t)(b*NK + k)*(VOL/4) + off4 + j*256];
            sp[k]  += p.x + p.y + p.z + p.w;
            sip[k] += p.x*iv.x + p.y*iv.y + p.z*iv.z + p.w*iv.w;
        }
    }
    #pragma unroll
    for (int k = 0; k < 4; ++k) {
        #pragma unroll
        for (int o = 32; o; o >>= 1) {
            sp[k]  += __shfl_down(sp[k],  o);
            sip[k] += __shfl_down(sip[k], o);
        }
    }
    __shared__ float sB[8][4];
    const int wid = t >> 6;
    if ((t & 63) == 0) {
        #pragma unroll
        for (int k = 0; k < 4; ++k) { sB[k][wid] = sp[k]; sB[4+k][wid] = sip[k]; }
    }
    __syncthreads();
    if (t < 8) {
        const float v = sB[t][0] + sB[t][1] + sB[t][2] + sB[t][3];
        atomicAdd(&red[((t < 4 ? 0 : 8) + b*NK + (t & 3))*WSS], v);
    }
}

// K2: fused wh-blur + d-blur + weights + reduction + final (ticket).
// Grid 512 = (vol 8) x (strip 16) x (d-quarter 4), 256 threads.
// TWO d-slices per iteration: 20 iterations x 1 barrier (was 40), two
// independent slice dataflows per wave (2x ILP to hide LDS/global latency),
// per-slice ring-shift and loop overhead halved. 4 staging buffers
// [parity][slice] — safe with one barrier/iter: a wave's iter-N reads
// precede its iter-N+1 barrier arrival; iter-N+2 writes follow it.
// LDS layout identical to round-0 (stride 33, full-width) => 0 conflicts.
__global__ __launch_bounds__(256, 2) void k_fused(
    const float* __restrict__ labels, const float* __restrict__ inputs,
    float* __restrict__ red, float* __restrict__ out)
{
    __shared__ float4 sW[2][2][16*SSTR + 8];
    __shared__ float sN[4], sD[4];

    const int dq    = blockIdx.x & 3;
    const int strip = (blockIdx.x >> 2) & 15;
    const int vol   = blockIdx.x >> 6;
    const int b = vol >> 2, kcls = vol & 3;
    const int d0 = dq * 32;
    const int t  = threadIdx.x;
    const float g1 = c_g[5], g2 = c_g[6], g3 = c_g[7], g4 = c_g[8];
    const float4 z4 = make_float4(0.f, 0.f, 0.f, 0.f);

    const float* __restrict__ src = labels + (size_t)vol*VOL;
    const float mean = red[(8+vol)*WSS] / (red[vol*WSS] + 20.97152f);

    // two w-blur sites per thread: (r0,c0) and (r0+8,c0), staged rows 0..15
    const int r0 = t >> 5, c0 = t & 31;
    const int r1 = r0 + 8;
    // h-blur / output site: global row strip*8+ho, float4 col wq
    const int ho = t >> 5, wq = t & 31;

    const int hA = strip*8 - 4 + r0;
    const int hB = strip*8 - 4 + r1;
    const bool vA = (unsigned)hA < 128u;
    const bool vB = (unsigned)hB < 128u;
    const float4* __restrict__ rowA = (const float4*)(src + (size_t)(vA ? hA : 0)*DIM);
    const float4* __restrict__ rowB = (const float4*)(src + (size_t)(vB ? hB : 0)*DIM);

    const size_t ob4 = (size_t)(strip*8 + ho)*(DIM/4) + wq;
    const float4* __restrict__ P4 = (const float4*)src + ob4;
    const float4* __restrict__ I4 = (const float4*)(inputs + (size_t)b*VOL) + ob4;

    // ring[k] holds h-blurred slice s0+k-8 (post-insert); 10 deep for 2 outputs
    float4 ring[10];
    #pragma unroll
    for (int i = 0; i < 10; ++i) ring[i] = z4;
    float numAcc = 0.f, denAcc = 0.f;

    auto ldA = [&](int s, float4& pv, float4& cv, float4& nx) {
        pv = cv = nx = z4;
        if (vA && (unsigned)s < 128u) {
            const float4* rp = rowA + (size_t)s*(SLICE/4);
            cv = rp[c0];
            if (c0 > 0)  pv = rp[c0-1];
            if (c0 < 31) nx = rp[c0+1];
        }
    };
    auto ldB = [&](int s, float4& pv, float4& cv, float4& nx) {
        pv = cv = nx = z4;
        if (vB && (unsigned)s < 128u) {
            const float4* rp = rowB + (size_t)s*(SLICE/4);
            cv = rp[c0];
            if (c0 > 0)  pv = rp[c0-1];
            if (c0 < 31) nx = rp[c0+1];
        }
    };

    // w-blur of a window triple -> one staged float4
    auto wblur = [&](const float4& pv, const float4& cv, const float4& nx) {
        float4 o;
        o.x = cv.x + g1*(pv.w+cv.y) + g2*(pv.z+cv.z) + g3*(pv.y+cv.w) + g4*(pv.x+nx.x);
        o.y = cv.y + g1*(cv.x+cv.z) + g2*(pv.w+cv.w) + g3*(pv.z+nx.x) + g4*(pv.y+nx.y);
        o.z = cv.z + g1*(cv.y+cv.w) + g2*(cv.x+nx.x) + g3*(pv.w+nx.y) + g4*(pv.z+nx.z);
        o.w = cv.w + g1*(cv.z+nx.x) + g2*(cv.y+nx.y) + g3*(cv.x+nx.z) + g4*(pv.w+nx.w);
        return o;
    };

    // windows: slice pair (s0, s0+1) in flight
    float4 A0pv,A0cv,A0nx, B0pv,B0cv,B0nx;   // slice s0
    float4 A1pv,A1cv,A1nx, B1pv,B1cv,B1nx;   // slice s0+1
    ldA(d0-4, A0pv,A0cv,A0nx);  ldB(d0-4, B0pv,B0cv,B0nx);
    ldA(d0-3, A1pv,A1cv,A1nx);  ldB(d0-3, B1pv,B1cv,B1nx);

    int pp = 0;
    for (int s0 = d0-4; s0 < d0+36; s0 += 2, pp ^= 1) {
        // ---- stage slice s0 into sW[pp][0], then refill windows with s0+2
        sW[pp][0][r0*SSTR + c0] = wblur(A0pv,A0cv,A0nx);
        sW[pp][0][r1*SSTR + c0] = wblur(B0pv,B0cv,B0nx);
        ldA(s0+2, A0pv,A0cv,A0nx);
        ldB(s0+2, B0pv,B0cv,B0nx);
        // ---- stage slice s0+1 into sW[pp][1], refill with s0+3
        sW[pp][1][r0*SSTR + c0] = wblur(A1pv,A1cv,A1nx);
        sW[pp][1][r1*SSTR + c0] = wblur(B1pv,B1cv,B1nx);
        ldA(s0+3, A1pv,A1cv,A1nx);
        ldB(s0+3, B1pv,B1cv,B1nx);

        const bool outStep = (s0 >= d0+4);
        float4 pc0 = z4, ic0 = z4, pc1 = z4, ic1 = z4;
        if (outStep) {                       // prefetch output-voxel P, I
            pc0 = P4[(size_t)(s0-4)*(SLICE/4)];
            ic0 = I4[(size_t)(s0-4)*(SLICE/4)];
            pc1 = P4[(size_t)(s0-3)*(SLICE/4)];
            ic1 = I4[(size_t)(s0-3)*(SLICE/4)];
        }

        __syncthreads();                     // ONE barrier per 2 slices

        // ---- h-blur both staged slices
        float4 acc0 = sW[pp][0][(ho+4)*SSTR + wq];
        float4 acc1 = sW[pp][1][(ho+4)*SSTR + wq];
        #pragma unroll
        for (int dt = 1; dt <= 4; ++dt) {
            const float g = c_g[4+dt];
            const float4 u0 = sW[pp][0][(ho+4-dt)*SSTR + wq];
            const float4 v0 = sW[pp][0][(ho+4+dt)*SSTR + wq];
            acc0.x += g*(u0.x+v0.x); acc0.y += g*(u0.y+v0.y);
            acc0.z += g*(u0.z+v0.z); acc0.w += g*(u0.w+v0.w);
            const float4 u1 = sW[pp][1][(ho+4-dt)*SSTR + wq];
            const float4 v1 = sW[pp][1][(ho+4+dt)*SSTR + wq];
            acc1.x += g*(u1.x+v1.x); acc1.y += g*(u1.y+v1.y);
            acc1.z += g*(u1.z+v1.z); acc1.w += g*(u1.w+v1.w);
        }

        // ---- ring shift by 2, insert (ring[k] = slice s0+k-8)
        #pragma unroll
        for (int i = 0; i < 8; ++i) ring[i] = ring[i+2];
        ring[8] = acc0;
        ring[9] = acc1;

        if (outStep) {
            // output slice s0-4: center ring[4], taps ring[0..8]
            float4 B0 = ring[4];
            // output slice s0-3: center ring[5], taps ring[1..9]
            float4 B1 = ring[5];
            #pragma unroll
            for (int dt = 1; dt <= 4; ++dt) {
                const float g = c_g[4+dt];
                B0.x += g*(ring[4+dt].x + ring[4-dt].x);
                B0.y += g*(ring[4+dt].y + ring[4-dt].y);
                B0.z += g*(ring[4+dt].z + ring[4-dt].z);
                B0.w += g*(ring[4+dt].w + ring[4-dt].w);
                B1.x += g*(ring[5+dt].x + ring[5-dt].x);
                B1.y += g*(ring[5+dt].y + ring[5-dt].y);
                B1.z += g*(ring[5+dt].z + ring[5-dt].z);
                B1.w += g*(ring[5+dt].w + ring[5-dt].w);
            }
            { float df = ic0.x - mean; df *= df; const float bw = B0.x * __expf(-df*df); numAcc += bw*pc0.x; denAcc += bw; }
            { float df = ic0.y - mean; df *= df; const float bw = B0.y * __expf(-df*df); numAcc += bw*pc0.y; denAcc += bw; }
            { float df = ic0.z - mean; df *= df; const float bw = B0.z * __expf(-df*df); numAcc += bw*pc0.z; denAcc += bw; }
            { float df = ic0.w - mean; df *= df; const float bw = B0.w * __expf(-df*df); numAcc += bw*pc0.w; denAcc += bw; }
            { float df = ic1.x - mean; df *= df; const float bw = B1.x * __expf(-df*df); numAcc += bw*pc1.x; denAcc += bw; }
            { float df = ic1.y - mean; df *= df; const float bw = B1.y * __expf(-df*df); numAcc += bw*pc1.y; denAcc += bw; }
            { float df = ic1.z - mean; df *= df; const float bw = B1.z * __expf(-df*df); numAcc += bw*pc1.z; denAcc += bw; }
            { float df = ic1.w - mean; df *= df; const float bw = B1.w * __expf(-df*df); numAcc += bw*pc1.w; denAcc += bw; }
        }
    }

    #pragma unroll
    for (int o = 32; o; o >>= 1) { numAcc += __shfl_down(numAcc, o); denAcc += __shfl_down(denAcc, o); }
    if ((t & 63) == 0) { sN[t >> 6] = numAcc; sD[t >> 6] = denAcc; }
    __syncthreads();
    if (t == 0) {
        atomicAdd(&red[(16+kcls)*WSS], sN[0]+sN[1]+sN[2]+sN[3]);
        atomicAdd(&red[(20+kcls)*WSS], sD[0]+sD[1]+sD[2]+sD[3]);
        __threadfence();
        const unsigned old = atomicAdd((unsigned int*)&red[DONE*WSS], 1u);
        if (old == 511u) {                   // grid = 512 blocks
            float loss = 0.f;
            #pragma unroll
            for (int k = 0; k < 4; ++k) {
                const float nu = atomicAdd(&red[(16+k)*WSS], 0.0f);
                const float de = atomicAdd(&red[(20+k)*WSS], 0.0f);
                loss += fabsf(nu / (de + 1e-6f));
            }
            out[0] = (float)NK - loss;
        }
    }
}

extern "C" void kernel_launch(void* const* d_in, const int* in_sizes, int n_in,
                              void* d_out, int out_size, void* d_ws, size_t ws_size,
                              hipStream_t stream)
{
    const float* labels = (const float*)d_in[0];   // (2,4,128,128,128)
    const float* inputs = (const float*)d_in[1];   // (2,1,128,128,128)
    float* out = (float*)d_out;
    float* red = (float*)d_ws;                     // 25 slots x 32-float stride

    hipMemsetAsync(red, 0, 25*WSS*sizeof(float), stream);
    k_sums<<<2*512, 256, 0, stream>>>(labels, inputs, red);
    k_fused<<<8*16*4, 256, 0, stream>>>(labels, inputs, red, out);
}